// Round 17
// baseline (786.367 us; speedup 1.0000x reference)
//
#include <hip/hip_runtime.h>
#include <cstdint>
#include <cstddef>

// SelfAttention: B=8, S=2048, D=512, fp32 in/out.
// R13: producer/consumer wave specialization (intra-block TLP).
// One 64-row block, 8 waves (512 thr, 2 waves/SIMD):
//   X waves 0-3: QK^T(r) + softmax -> P(r), alpha(r), lpart(r) [dbl-buffered]
//   Y waves 4-7: O += P(r-1) V(r-1), l_y accumulated in registers.
// X and Y run CONCURRENTLY between block-wide barriers (2/round vs R9's 4/kt);
// phase C leaves the critical path. R9-proven pieces reused: swizzled K/Q
// staging, 32x32x16 swapped QK^T, PSTR=68 b64 P path, vf global->reg.
// Regs: acc 128 + max(X ~100, Y ~110) ~ 240 <= 256 (LB(512,1)).
// LDS: Q 64K + K 64K + P 2x8.5K + m/a/l 2K = 147 KB, 1 block/CU.
// ws: [qh 16M][kh 16M][vh 16M][vt 16M (xh aliases)][Wt 1.5M] = 65.5 MiB.

#define SEQ 2048
#define DIM 512
#define NB 8
#define BSZ (NB * SEQ)
#define KT 64
#define NT (SEQ / KT)
#define QROWS 64

typedef __attribute__((ext_vector_type(8))) _Float16 half8;
typedef __attribute__((ext_vector_type(4))) _Float16 half4;
typedef __attribute__((ext_vector_type(2))) __fp16 fp16x2;
typedef __attribute__((ext_vector_type(4))) float f32x4;
typedef __attribute__((ext_vector_type(16))) float f32x16;

__device__ __forceinline__ unsigned short f2h(float f) {
  _Float16 h = (_Float16)f;
  return __builtin_bit_cast(unsigned short, h);
}
__device__ __forceinline__ half8 ld_frag(const unsigned short* p) {
  return *(const half8*)(const void*)p;
}
__device__ __forceinline__ void gl_lds16(const unsigned short* g, unsigned short* l) {
  __builtin_amdgcn_global_load_lds(
      (__attribute__((address_space(1))) void*)g,
      (__attribute__((address_space(3))) void*)l, 16, 0, 0);
}
// Fused waitcnt+barrier (single asm block: nothing schedules between them).
__device__ __forceinline__ void bar_lgkm() {
  asm volatile("s_waitcnt lgkmcnt(0)\ns_barrier" ::: "memory");
}
__device__ __forceinline__ void bar_lgkm_vm0() {
  asm volatile("s_waitcnt lgkmcnt(0) vmcnt(0)\ns_barrier" ::: "memory");
}

// ---------------------------------------------------------------------------
__global__ __launch_bounds__(256) void cvt_x_kernel(
    const float* __restrict__ X, unsigned short* __restrict__ xh)
{
  size_t i0 = ((size_t)blockIdx.x * 256 + threadIdx.x) * 8;
  float4 a = *(const float4*)&X[i0];
  float4 b = *(const float4*)&X[i0 + 4];
  ushort4 o0; o0.x = f2h(a.x); o0.y = f2h(a.y); o0.z = f2h(a.z); o0.w = f2h(a.w);
  ushort4 o1; o1.x = f2h(b.x); o1.y = f2h(b.y); o1.z = f2h(b.z); o1.w = f2h(b.w);
  *(ushort4*)&xh[i0] = o0;
  *(ushort4*)&xh[i0 + 4] = o1;
}

// ---------------------------------------------------------------------------
__global__ __launch_bounds__(256) void cvt_w_kernel(
    const float* __restrict__ Wq, const float* __restrict__ Wk,
    const float* __restrict__ Wv, unsigned short* __restrict__ Wt)
{
  const int z = blockIdx.z;
  const float* W = (z == 0) ? Wq : (z == 1) ? Wk : Wv;
  unsigned short* out = Wt + (size_t)z * DIM * DIM;
  const int k0 = blockIdx.x * 64, n0 = blockIdx.y * 64;
  const int t = threadIdx.x;
  __shared__ unsigned short tl[64 * 72];
#pragma unroll
  for (int i = 0; i < 4; i++) {
    int f = t + 256 * i;
    int kr = f >> 4, c4 = (f & 15) * 4;
    float4 v = *(const float4*)&W[(size_t)(k0 + kr) * DIM + n0 + c4];
    tl[(c4 + 0) * 72 + kr] = f2h(v.x);
    tl[(c4 + 1) * 72 + kr] = f2h(v.y);
    tl[(c4 + 2) * 72 + kr] = f2h(v.z);
    tl[(c4 + 3) * 72 + kr] = f2h(v.w);
  }
  __syncthreads();
#pragma unroll
  for (int i = 0; i < 2; i++) {
    int f = t + 256 * i;
    int nr = f >> 3, k8 = (f & 7) * 8;
    *(uint4*)&out[(size_t)(n0 + nr) * DIM + k0 + k8] = *(const uint4*)&tl[nr * 72 + k8];
  }
}

// ---------------------------------------------------------------------------
// proj (unchanged): qkv[z] = fp16(xh @ Wt[z]^T + b[z]).
// ---------------------------------------------------------------------------
__global__ __launch_bounds__(256) void proj_kernel(
    const unsigned short* __restrict__ xh, const unsigned short* __restrict__ Wt,
    const float* __restrict__ bq, const float* __restrict__ bk,
    const float* __restrict__ bv, unsigned short* __restrict__ outbase)
{
  const int z = blockIdx.z;
  const unsigned short* Wz = Wt + (size_t)z * DIM * DIM;
  const float* bias = (z == 0) ? bq : (z == 1) ? bk : bv;
  unsigned short* out = outbase + (size_t)z * BSZ * DIM;
  const int m0 = blockIdx.x * 128, n0 = blockIdx.y * 128;
  const int t = threadIdx.x, lane = t & 63, wave = t >> 6;
  const int wrow = (wave >> 1) * 64, wcol = (wave & 1) * 64;
  const int lr = lane & 15, lq = (lane >> 4) * 8;

  __shared__ unsigned short sm[128 * 132];
  unsigned short* As = sm;
  unsigned short* Bs = sm + 128 * 64;

  f32x4 acc[4][4];
  const f32x4 zero = {0.f, 0.f, 0.f, 0.f};
#pragma unroll
  for (int r = 0; r < 4; r++)
#pragma unroll
    for (int c = 0; c < 4; c++) acc[r][c] = zero;

  for (int k0 = 0; k0 < DIM; k0 += 64) {
    __syncthreads();
#pragma unroll
    for (int i = 0; i < 4; i++) {
      int f = t + 256 * i;
      int row = f >> 3, c8 = (f & 7) * 8;
      gl_lds16(&xh[(size_t)(m0 + row) * DIM + k0 + c8], &As[i * 2048 + wave * 512]);
      gl_lds16(&Wz[(size_t)(n0 + row) * DIM + k0 + c8], &Bs[i * 2048 + wave * 512]);
    }
    __syncthreads();
#pragma unroll
    for (int kk = 0; kk < 64; kk += 32) {
      half8 a[4], b[4];
#pragma unroll
      for (int r = 0; r < 4; r++) a[r] = ld_frag(&As[(wrow + 16 * r + lr) * 64 + kk + lq]);
#pragma unroll
      for (int c = 0; c < 4; c++) b[c] = ld_frag(&Bs[(wcol + 16 * c + lr) * 64 + kk + lq]);
#pragma unroll
      for (int r = 0; r < 4; r++)
#pragma unroll
        for (int c = 0; c < 4; c++)
          acc[r][c] = __builtin_amdgcn_mfma_f32_16x16x32_f16(a[r], b[c], acc[r][c], 0, 0, 0);
    }
  }
  __syncthreads();
#pragma unroll
  for (int c = 0; c < 4; c++) {
    float bb = bias[n0 + wcol + 16 * c + lr];
#pragma unroll
    for (int r = 0; r < 4; r++)
#pragma unroll
      for (int e = 0; e < 4; e++)
        sm[(wrow + 16 * r + (lane >> 4) * 4 + e) * 132 + wcol + 16 * c + lr] =
            f2h(acc[r][c][e] + bb);
  }
  __syncthreads();
#pragma unroll
  for (int i = 0; i < 8; i++) {
    int f = t + 256 * i;
    int row = f >> 4, c8 = (f & 15) * 8;
    *(uint4*)&out[(size_t)(m0 + row) * DIM + n0 + c8] = *(const uint4*)&sm[row * 132 + c8];
  }
}

// ---------------------------------------------------------------------------
__global__ __launch_bounds__(256) void vtrans_kernel(
    const unsigned short* __restrict__ vh, unsigned short* __restrict__ vt)
{
  const int b = blockIdx.z;
  const int s0 = blockIdx.x * 64, n0 = blockIdx.y * 64;
  const int t = threadIdx.x;
  __shared__ unsigned short tl[64 * 72];
#pragma unroll
  for (int i = 0; i < 2; i++) {
    int f = t + 256 * i;
    int sr = f >> 3, c8 = (f & 7) * 8;
    uint4 raw = *(const uint4*)&vh[((size_t)b * SEQ + s0 + sr) * DIM + n0 + c8];
    unsigned short u[8];
    *(uint4*)u = raw;
#pragma unroll
    for (int j = 0; j < 8; j++) tl[(c8 + j) * 72 + sr] = u[j];
  }
  __syncthreads();
#pragma unroll
  for (int i = 0; i < 2; i++) {
    int f = t + 256 * i;
    int nr = f >> 3, s8 = (f & 7) * 8;
    *(uint4*)&vt[((size_t)b * DIM + n0 + nr) * SEQ + s0 + s8] = *(const uint4*)&tl[nr * 72 + s8];
  }
}

// ---------------------------------------------------------------------------
// flash R13: producer/consumer. 64 Q rows, 8 waves.
// X (wave<4, kh=wave&1, rh=wave>>1): per round r<NT:
//   sub1: S^T quadrant = K·Q^T (32 mfma_32x32x16, K+Q from LDS); row max;
//         mpart[kh] write.
//   sub2 (after mid-bar): issue K(r+1); combine kh-max; alpha->abuf[r&1];
//         exp, P b64 -> Pbuf[r&1]; psum -> lpart[r&1].
// Y (wave>=4, yw=wave&3, d-slice yw*128): per round r>0 (tile p=r-1):
//   sub1: issue vf (V^T global->reg); rescale acc & l_y by abuf[p&1];
//         l_y += lpart[p&1]; pf from Pbuf[p&1]; MFMAs dc0-3.
//   sub2: MFMAs dc4-7.
// 2 barriers/round; X softmax overlaps Y MFMA on the same SIMDs.
// ---------------------------------------------------------------------------
#define PSTR 68   // Pbuf row stride (halves): b64 P-writes conflict-free
#define OSTR 516  // Obuf row stride (floats)

__global__ __launch_bounds__(512, 1) void flash_kernel(
    const unsigned short* __restrict__ Qb, const unsigned short* __restrict__ Kb,
    const unsigned short* __restrict__ Vtb, float* __restrict__ Ob)
{
  const int zb = blockIdx.x & 7;              // batch -> XCD affinity
  const int q0 = (blockIdx.x >> 3) * QROWS;   // q-tile base row
  const unsigned short* Q = Qb + (size_t)zb * SEQ * DIM;
  const unsigned short* K = Kb + (size_t)zb * SEQ * DIM;
  const unsigned short* V = Vtb + (size_t)zb * DIM * SEQ;  // [d][s]
  float* Out = Ob + (size_t)zb * SEQ * DIM;

  const int t = threadIdx.x, lane = t & 63, wave = t >> 6;
  const int l31 = lane & 31, hi = lane >> 5;
  const int kh = wave & 1, rh = (wave >> 1) & 1;  // X decomposition
  const int yw = wave & 3;                        // Y d-slice index
  const int lr = lane & 15, lq4 = lane >> 4;
  const float L2E = 1.4426950408889634f;

  // LDS carve (halves): Qbuf 32768 | Kbuf 32768 | Pbuf 2x64xPSTR=8704 |
  // mpart 256 (2x64 f32) | abuf 256 (2x64 f32) | lpart 512 (2x2x64 f32)
  // = 75264 halves = 150528 B -> 1 block/CU.
  __shared__ unsigned short lds[75264];
  unsigned short* Qbuf = lds;                   // [64 rows][512], swizzled
  unsigned short* Kbuf = lds + 32768;           // [64 keys][512], swizzled
  unsigned short* Pbuf = lds + 65536;           // [2][64][PSTR]
  float* mpart = (float*)(lds + 65536 + 2 * 64 * PSTR);  // [2 kh][64 rows]
  float* abuf  = mpart + 128;                   // [2 rb][64 rows]
  float* lpart = abuf + 128;                    // [2 rb][2 kh][64 rows]

  // staging offsets (X waves, t<256): tile [64 rows][512 halves],
  // source chunk = lds chunk ^ (row&7).
  int koff[16];
#pragma unroll
  for (int i = 0; i < 16; i++) {
    int f = (t & 255) + 256 * i;
    int row = f >> 6, c = f & 63;
    koff[i] = row * DIM + (c ^ (row & 7)) * 8;
  }

  // ---- prologue: X waves stage Q (resident) and K(0) ----
  if (wave < 4) {
#pragma unroll
    for (int i = 0; i < 16; i++)
      gl_lds16(&Q[(size_t)q0 * DIM + koff[i]], &Qbuf[i * 2048 + wave * 512]);
#pragma unroll
    for (int i = 0; i < 16; i++)
      gl_lds16(&K[koff[i]], &Kbuf[i * 2048 + wave * 512]);
  }

  // ---- running state ----
  f32x4 acc[32];  // Y: [rg 0..3][dc 0..7]: row rg*16+lq4*4+e, d yw*128+dc*16+lr
  const f32x4 zero = {0.f, 0.f, 0.f, 0.f};
#pragma unroll
  for (int ob = 0; ob < 32; ob++) acc[ob] = zero;
  float l_y[4][4];  // Y: softmax denominator per (rg,e) row
#pragma unroll
  for (int rg = 0; rg < 4; rg++)
#pragma unroll
    for (int e = 0; e < 4; e++) l_y[rg][e] = 0.f;
  float m_run = -__builtin_inff();  // X: running max for qrow rh*32+l31

  const int keyrow = kh * 32 + l31, ksw = keyrow & 7;
  const int qrow = rh * 32 + l31, qsw = qrow & 7;
  const unsigned short* Kc = Kbuf + keyrow * 512;
  const unsigned short* Qc = Qbuf + qrow * 512;

  for (int r = 0; r <= NT; r++) {
    bar_lgkm_vm0();  // round start: K(r) landed; P/abuf/lpart(r-1) visible

    f32x16 sacc;   // X live across mid-bar
    float mx = 0.f;
    half8 vf[16];  // Y live across mid-bar
    half8 pf[4][2];

    if (wave < 4) {
      if (r < NT) {
        // ===== X sub1: S^T quadrant = K·Q^T (2 chains of 16) =====
        f32x16 s0c = {0.f, 0.f, 0.f, 0.f, 0.f, 0.f, 0.f, 0.f,
                      0.f, 0.f, 0.f, 0.f, 0.f, 0.f, 0.f, 0.f};
        f32x16 s1c = s0c;
        __builtin_amdgcn_s_setprio(1);
#pragma unroll
        for (int j = 0; j < 16; j++) {
          half8 kf0 = ld_frag(&Kc[((2 * j + hi) ^ ksw) << 3]);
          half8 qv0 = ld_frag(&Qc[((2 * j + hi) ^ qsw) << 3]);
          half8 kf1 = ld_frag(&Kc[((2 * (j + 16) + hi) ^ ksw) << 3]);
          half8 qv1 = ld_frag(&Qc[((2 * (j + 16) + hi) ^ qsw) << 3]);
          s0c = __builtin_amdgcn_mfma_f32_32x32x16_f16(kf0, qv0, s0c, 0, 0, 0);
          s1c = __builtin_amdgcn_mfma_f32_32x32x16_f16(kf1, qv1, s1c, 0, 0, 0);
        }
        __builtin_amdgcn_s_setprio(0);
        sacc = s0c + s1c;
        mx = sacc[0];
#pragma unroll
        for (int i2 = 1; i2 < 16; i2++) mx = fmaxf(mx, sacc[i2]);
        mx = fmaxf(mx, __shfl_xor(mx, 32, 64));
        if (lane < 32) mpart[kh * 64 + rh * 32 + lane] = mx;
      }
    } else {
      if (r > 0) {
        // ===== Y sub1: PV for tile p = r-1 =====
        const int pb = (r - 1) & 1;
        const unsigned short* Vb =
            V + (size_t)(yw * 128 + lr) * SEQ + (size_t)(r - 1) * KT + lq4 * 8;
#pragma unroll
        for (int dc = 0; dc < 8; dc++)
#pragma unroll
          for (int ks = 0; ks < 2; ks++)
            vf[dc * 2 + ks] = ld_frag(Vb + (size_t)dc * 16 * SEQ + ks * 32);
        // rescale acc and l_y by alpha(p); add lsum(p)
#pragma unroll
        for (int rg = 0; rg < 4; rg++)
#pragma unroll
          for (int e = 0; e < 4; e++) {
            int row = rg * 16 + lq4 * 4 + e;
            float a = abuf[pb * 64 + row];
            float ls = lpart[pb * 128 + row] + lpart[pb * 128 + 64 + row];
            l_y[rg][e] = a * l_y[rg][e] + ls;
#pragma unroll
            for (int dc = 0; dc < 8; dc++) acc[rg * 8 + dc][e] *= a;
          }
        // P fragments (b64 pair reads, PSTR=68 conflict-free)
#pragma unroll
        for (int rg = 0; rg < 4; rg++)
#pragma unroll
          for (int ks = 0; ks < 2; ks++) {
            const unsigned short* pp =
                &Pbuf[pb * 64 * PSTR + (rg * 16 + lr) * PSTR + ks * 32 + lq4 * 8];
            half4 lo = *(const half4*)(const void*)pp;
            half4 h2 = *(const half4*)(const void*)(pp + 4);
            half8 v;
#pragma unroll
            for (int q = 0; q < 4; q++) { v[q] = lo[q]; v[4 + q] = h2[q]; }
            pf[rg][ks] = v;
          }
        __builtin_amdgcn_s_setprio(1);
#pragma unroll
        for (int dc = 0; dc < 4; dc++)
#pragma unroll
          for (int rg = 0; rg < 4; rg++) {
            acc[rg * 8 + dc] = __builtin_amdgcn_mfma_f32_16x16x32_f16(
                pf[rg][0], vf[dc * 2 + 0], acc[rg * 8 + dc], 0, 0, 0);
            acc[rg * 8 + dc] = __builtin_amdgcn_mfma_f32_16x16x32_f16(
                pf[rg][1], vf[dc * 2 + 1], acc[rg * 8 + dc], 0, 0, 0);
          }
        __builtin_amdgcn_s_setprio(0);
      }
    }

    bar_lgkm();  // mid: mpart visible; Kbuf/Pbuf(r-1) reads drained block-wide

    if (wave < 4) {
      // issue K(r+1) into Kbuf (all reads drained at mid-bar)
      if (r + 1 < NT) {
        const unsigned short* Kt = K + (size_t)(r + 1) * KT * DIM;
#pragma unroll
        for (int i = 0; i < 16; i++)
          gl_lds16(&Kt[koff[i]], &Kbuf[i * 2048 + wave * 512]);
      }
      if (r < NT) {
        // ===== X sub2: softmax finish, P/alpha/lpart(r) publish =====
        const int rb = r & 1;
        float mo = mpart[(kh ^ 1) * 64 + rh * 32 + l31];
        float mnew = fmaxf(m_run, fmaxf(mx, mo));
        float alpha = exp2f((m_run - mnew) * L2E);
        m_run = mnew;
        if (kh == 0 && lane < 32) abuf[rb * 64 + rh * 32 + lane] = alpha;
        float psum = 0.f;
#pragma unroll
        for (int w2 = 0; w2 < 4; w2++) {
          float p0 = exp2f((sacc[4 * w2 + 0] - mnew) * L2E);
          float p1 = exp2f((sacc[4 * w2 + 1] - mnew) * L2E);
          float p2 = exp2f((sacc[4 * w2 + 2] - mnew) * L2E);
          float p3 = exp2f((sacc[4 * w2 + 3] - mnew) * L2E);
          psum += (p0 + p1) + (p2 + p3);
          fp16x2 pa = __builtin_amdgcn_cvt_pkrtz(p0, p1);
          fp16x2 pb2 = __builtin_amdgcn_cvt_pkrtz(p2, p3);
          unsigned long long both =
              ((unsigned long long)__builtin_bit_cast(unsigned int, pb2) << 32) |
              __builtin_bit_cast(unsigned int, pa);
          *(unsigned long long*)&Pbuf[rb * 64 * PSTR + qrow * PSTR + kh * 32 +
                                      w2 * 8 + 4 * hi] = both;
        }
        psum += __shfl_xor(psum, 32, 64);
        if (lane < 32) lpart[rb * 128 + kh * 64 + rh * 32 + lane] = psum;
      }
    } else {
      if (r > 0) {
        // ===== Y sub2: remaining MFMAs (dc 4..7) =====
        __builtin_amdgcn_s_setprio(1);
#pragma unroll
        for (int dc = 4; dc < 8; dc++)
#pragma unroll
          for (int rg = 0; rg < 4; rg++) {
            acc[rg * 8 + dc] = __builtin_amdgcn_mfma_f32_16x16x32_f16(
                pf[rg][0], vf[dc * 2 + 0], acc[rg * 8 + dc], 0, 0, 0);
            acc[rg * 8 + dc] = __builtin_amdgcn_mfma_f32_16x16x32_f16(
                pf[rg][1], vf[dc * 2 + 1], acc[rg * 8 + dc], 0, 0, 0);
          }
        __builtin_amdgcn_s_setprio(0);
      }
    }
  }

  bar_lgkm_vm0();  // all rounds done; LDS quiesced before Obuf reuse

  // ---- finalize: Y waves write O/l via LDS repack, all waves store ----
  float linv[4][4];
  if (wave >= 4) {
#pragma unroll
    for (int rg = 0; rg < 4; rg++)
#pragma unroll
      for (int e = 0; e < 4; e++) linv[rg][e] = 1.0f / l_y[rg][e];
  }
  float* Obuf = (float*)lds;  // 32 x OSTR floats = 66 KB over Qbuf/Kbuf
#pragma unroll
  for (int h = 0; h < 2; h++) {
    __syncthreads();
    if (wave >= 4) {
#pragma unroll
      for (int r2 = 0; r2 < 2; r2++) {
        int rg = h * 2 + r2;
#pragma unroll
        for (int e = 0; e < 4; e++) {
          int rowh = r2 * 16 + lq4 * 4 + e;
#pragma unroll
          for (int dc = 0; dc < 8; dc++)
            Obuf[rowh * OSTR + yw * 128 + dc * 16 + lr] =
                acc[rg * 8 + dc][e] * linv[rg][e];
        }
      }
    }
    __syncthreads();
#pragma unroll
    for (int i = 0; i < 8; i++) {
      int f = t + 512 * i;
      int rowh = f >> 7, c4 = (f & 127) * 4;
      *(float4*)&Out[(size_t)(q0 + h * 32 + rowh) * DIM + c4] =
          *(const float4*)&Obuf[rowh * OSTR + c4];
    }
  }
}

// ---------------------------------------------------------------------------
extern "C" void kernel_launch(void* const* d_in, const int* in_sizes, int n_in,
                              void* d_out, int out_size, void* d_ws, size_t ws_size,
                              hipStream_t stream)
{
  const float* X  = (const float*)d_in[0];
  const float* Wq = (const float*)d_in[1];
  const float* bq = (const float*)d_in[2];
  const float* Wk = (const float*)d_in[3];
  const float* bk = (const float*)d_in[4];
  const float* Wv = (const float*)d_in[5];
  const float* bv = (const float*)d_in[6];
  float* Out = (float*)d_out;

  char* ws = (char*)d_ws;
  const size_t MB = 1u << 20;
  unsigned short* qh = (unsigned short*)(ws);            // 16 MiB
  unsigned short* kh = (unsigned short*)(ws + 16 * MB);  // 16 MiB (proj z=1)
  unsigned short* vh = (unsigned short*)(ws + 32 * MB);  // 16 MiB (proj z=2)
  unsigned short* vt = (unsigned short*)(ws + 48 * MB);  // 16 MiB
  unsigned short* xh = (unsigned short*)(ws + 48 * MB);  // alias vt: dead pre-vtrans
  unsigned short* Wt = (unsigned short*)(ws + 64 * MB);  // 1.5 MiB

  cvt_x_kernel<<<dim3(BSZ * DIM / 2048), 256, 0, stream>>>(X, xh);
  cvt_w_kernel<<<dim3(8, 8, 3), 256, 0, stream>>>(Wq, Wk, Wv, Wt);
  proj_kernel<<<dim3(BSZ / 128, DIM / 128, 3), 256, 0, stream>>>(
      xh, Wt, bq, bk, bv, qh);
  vtrans_kernel<<<dim3(SEQ / 64, DIM / 64, NB), 256, 0, stream>>>(vh, vt);
  flash_kernel<<<dim3(NB * SEQ / QROWS), 512, 0, stream>>>(qh, kh, vt, Out);
}